// Round 16
// baseline (427.885 us; speedup 1.0000x reference)
//
#include <hip/hip_runtime.h>

// ---------- types / helpers ----------
typedef __attribute__((ext_vector_type(8))) short short8;
typedef __attribute__((ext_vector_type(4))) float f32x4;

#define AS1C(p) ((const __attribute__((address_space(1))) void*)(p))
#define AS3(p)  ((__attribute__((address_space(3))) void*)(p))

__device__ __forceinline__ unsigned short f2bf(float f) {
  unsigned int u = __float_as_uint(f);
  return (unsigned short)((u + 0x7fffu + ((u >> 16) & 1u)) >> 16);
}

__device__ __forceinline__ void gload16(const void* g, void* l) {
  // 16B global -> LDS direct; LDS dest = wave-uniform base + lane*16
  __builtin_amdgcn_global_load_lds(AS1C(g), AS3(l), 16, 0, 0);
}

// exp(s/8) = exp2(s * 0.125*log2(e))
#define EXP_C 0.18033688011112042f

// ---------- merged prep: W transpose (0..4095) + mask pack (4096..36863) + f32->bf16 conv (36864..61439) ----------
__global__ __launch_bounds__(256) void prep_kernel(const float* __restrict__ W0,
                                                   const float* __restrict__ W1,
                                                   const float* __restrict__ W2,
                                                   const float* __restrict__ W3,
                                                   unsigned short* __restrict__ WtBase,
                                                   const int* __restrict__ m,
                                                   unsigned int* __restrict__ bitsT,
                                                   const float* __restrict__ s0,
                                                   const float* __restrict__ s1,
                                                   const float* __restrict__ s2,
                                                   unsigned short* __restrict__ d0,
                                                   unsigned short* __restrict__ d1,
                                                   unsigned short* __restrict__ d2) {
  int bid = blockIdx.x;
  if (bid < 4096) {
    __shared__ float t[32][33];
    int z = bid >> 10;              // 0..3: which W
    int rb = bid & 1023;            // 32x32 tile id
    int bx = (rb & 31) * 32, by = (rb >> 5) * 32;
    const float* W = (z == 0) ? W0 : (z == 1) ? W1 : (z == 2) ? W2 : W3;
    unsigned short* Wt = WtBase + (size_t)z * 1024 * 1024;
    int tx = threadIdx.x & 31, ty = threadIdx.x >> 5;  // 32 x 8
#pragma unroll
    for (int i = 0; i < 4; ++i) {
      int r = ty + i * 8;
      t[r][tx] = W[(size_t)(by + r) * 1024 + bx + tx];
    }
    __syncthreads();
#pragma unroll
    for (int i = 0; i < 4; ++i) {
      int r = ty + i * 8;
      Wt[(size_t)(bx + r) * 1024 + by + tx] = f2bf(t[tx][r]);
    }
  } else if (bid < 36864) {
    int i = (bid - 4096) * 256 + threadIdx.x;   // over 8M mask elements: b*1M + q*1024 + k
    unsigned long long bl = __ballot(m[i] != 0);
    if ((threadIdx.x & 63) == 0) {
      int b_ = i >> 20, q = (i >> 10) & 1023, k = i & 1023;
      int w = k >> 5;
      bitsT[b_ * 32768 + w * 1024 + q]       = (unsigned int)bl;
      bitsT[b_ * 32768 + (w + 1) * 1024 + q] = (unsigned int)(bl >> 32);
    }
  } else {
    int cb = bid - 36864;                       // 0..24575
    int z = cb >> 13;                           // 0..2 (8192 blocks each)
    const float* in = (z == 0) ? s0 : (z == 1) ? s1 : s2;
    unsigned short* out = (z == 0) ? d0 : (z == 1) ? d1 : d2;
    int i = (cb & 8191) * 256 + threadIdx.x;    // over 2M float4
    float4 v = ((const float4*)in)[i];
    ushort4 o;
    o.x = f2bf(v.x); o.y = f2bf(v.y); o.z = f2bf(v.z); o.w = f2bf(v.w);
    ((ushort4*)out)[i] = o;
  }
}

// ---------- standalone f32 -> bf16 convert (small-ws fallback path) ----------
__global__ __launch_bounds__(256) void conv_bf16(const float* __restrict__ in,
                                                 unsigned short* __restrict__ out, int n4) {
  int i = blockIdx.x * 256 + threadIdx.x;
  if (i >= n4) return;
  float4 v = ((const float4*)in)[i];
  ushort4 o;
  o.x = f2bf(v.x); o.y = f2bf(v.y); o.z = f2bf(v.z); o.w = f2bf(v.w);
  ((ushort4*)out)[i] = o;
}

// ---------- v [128][1024][64] bf16 -> vt [128][64][1024] bf16 (raw flat view) ----------
__global__ __launch_bounds__(256) void transpose_v(const unsigned short* __restrict__ v,
                                                   unsigned short* __restrict__ vt) {
  __shared__ unsigned short t[32][33];
  int b = blockIdx.z;
  int bx = blockIdx.x * 32;  // d tile (0,32)
  int by = blockIdx.y * 32;  // k tile
  int tx = threadIdx.x & 31, ty = threadIdx.x >> 5;
#pragma unroll
  for (int i = 0; i < 4; ++i) {
    int r = ty + i * 8;
    t[r][tx] = v[(size_t)b * 65536 + (size_t)(by + r) * 64 + bx + tx];
  }
  __syncthreads();
#pragma unroll
  for (int i = 0; i < 4; ++i) {
    int r = ty + i * 8;
    vt[(size_t)b * 65536 + (size_t)(bx + r) * 1024 + by + tx] = t[tx][r];
  }
}

// ---------- bf16 GEMM tile body, BK=64 (R14-proven) ----------
// MODE 0: Cb = bf16(acc + bias).  MODE 1: Cf = acc + bias + res (f32).
template <int MODE>
__device__ __forceinline__ void gemm_body(
    const unsigned short* __restrict__ A, const unsigned short* __restrict__ Bt,
    const float* __restrict__ bias, const float* __restrict__ res,
    unsigned short* __restrict__ Cb, float* __restrict__ Cf,
    unsigned short* lA, unsigned short* lB) {
  const int K = 1024, N = 1024;
  const int tid = threadIdx.x;
  const int wave = tid >> 6, lane = tid & 63;
  const int row_l = lane & 15, kg = lane >> 4;
  const int wg = blockIdx.y * 8 + blockIdx.x;
  const int idx = (wg & 7) * 64 + (wg >> 3);
  const int m0 = (idx >> 3) * 128, n0 = (idx & 7) * 128;
  const int wm = (wave >> 1) * 64, wn = (wave & 1) * 64;
  f32x4 acc[4][4] = {};

  for (int k0 = 0; k0 < K; k0 += 64) {
    __syncthreads();
#pragma unroll
    for (int it = 0; it < 4; ++it) {
      int c = wave * 64 + it * 256 + lane;
      int r = c >> 3, ch = c & 7;
      int sch = ch ^ (r & 7);
      gload16(A + (size_t)(m0 + r) * K + k0 + sch * 8, lA + (wave * 64 + it * 256) * 8);
      gload16(Bt + (size_t)(n0 + r) * K + k0 + sch * 8, lB + (wave * 64 + it * 256) * 8);
    }
    __syncthreads();
#pragma unroll
    for (int kk = 0; kk < 2; ++kk) {
      short8 af[4], bfr[4];
#pragma unroll
      for (int t = 0; t < 4; ++t) {
        int ra = wm + t * 16 + row_l;
        af[t] = *(const short8*)(lA + ra * 64 + (((kk * 4 + kg) ^ (ra & 7)) << 3));
        int rb = wn + t * 16 + row_l;
        bfr[t] = *(const short8*)(lB + rb * 64 + (((kk * 4 + kg) ^ (rb & 7)) << 3));
      }
      __builtin_amdgcn_s_setprio(1);
#pragma unroll
      for (int mt = 0; mt < 4; ++mt)
#pragma unroll
        for (int nt = 0; nt < 4; ++nt)
          acc[mt][nt] = __builtin_amdgcn_mfma_f32_16x16x32_bf16(af[mt], bfr[nt], acc[mt][nt], 0, 0, 0);
      __builtin_amdgcn_s_setprio(0);
    }
  }
#pragma unroll
  for (int mt = 0; mt < 4; ++mt)
#pragma unroll
    for (int nt = 0; nt < 4; ++nt)
#pragma unroll
      for (int r = 0; r < 4; ++r) {
        int grow = m0 + wm + mt * 16 + kg * 4 + r;
        int gcol = n0 + wn + nt * 16 + row_l;
        float v = acc[mt][nt][r] + bias[gcol];
        if (MODE == 0) {
          Cb[(size_t)grow * N + gcol] = f2bf(v);
        } else {
          v += res[(size_t)grow * N + gcol];
          Cf[(size_t)grow * N + gcol] = v;
        }
      }
}

// q,k,v projections in one launch (z picks tensors).
__global__ __launch_bounds__(256) void gemm_qkv_kernel(
    const unsigned short* __restrict__ A0, const unsigned short* __restrict__ A1,
    const unsigned short* __restrict__ A2, const unsigned short* __restrict__ WtBase,
    const float* __restrict__ b0, const float* __restrict__ b1, const float* __restrict__ b2,
    unsigned short* __restrict__ C0, unsigned short* __restrict__ C1,
    unsigned short* __restrict__ C2) {
  __shared__ unsigned short lA[128 * 64];
  __shared__ unsigned short lB[128 * 64];
  int z = blockIdx.z;
  const unsigned short* A = (z == 0) ? A0 : (z == 1) ? A1 : A2;
  const float* bias = (z == 0) ? b0 : (z == 1) ? b1 : b2;
  unsigned short* C = (z == 0) ? C0 : (z == 1) ? C1 : C2;
  gemm_body<0>(A, WtBase + (size_t)z * 1024 * 1024, bias, nullptr, C, nullptr, lA, lB);
}

__global__ __launch_bounds__(256) void gemm_out_kernel(
    const unsigned short* __restrict__ A, const unsigned short* __restrict__ Bt,
    const float* __restrict__ bias, const float* __restrict__ res, float* __restrict__ Cf) {
  __shared__ unsigned short lA[128 * 64];
  __shared__ unsigned short lB[128 * 64];
  gemm_body<1>(A, Bt, bias, res, nullptr, Cf, lA, lB);
}

// ---------- attention: TWO q-tiles per block (A=q0, B=q0+64), swapped-QK, NT stores ----------
// Structure: pass1(A) -> MID-LOOP {pass1(B) fused with pass2(A): one K/V stage per kt
// serves both} -> pass2(B). The mid-loop interleaves read/MFMA work (B's sums) with
// A's NT write stream every iteration, and K staging drops 64->48 tiles per 128 q rows.
// LDS 32KB: lQ 16KB (QA+QB; later lP_A at 0 / lP_B at +4096) + lK 8KB + lV 8KB.
__global__ __launch_bounds__(256) void attn_kernel(
    const unsigned short* __restrict__ Q,    // [128][1024][64]
    const unsigned short* __restrict__ Km,   // [128][1024][64]
    const unsigned short* __restrict__ Vt,   // [128][64][1024]
    const unsigned int* __restrict__ mbitsT, // [8][32 kwords][1024 q]
    float* __restrict__ attn,                // [128][1024][1024]
    unsigned short* __restrict__ ctx) {      // [128][1024][64]
  __shared__ unsigned short lQ[128 * 64];    // QA+QB; later lP_A / lP_B
  __shared__ unsigned short lK[64 * 64];
  __shared__ unsigned short lV[64 * 64];     // [d][k]
  const int tid = threadIdx.x, wave = tid >> 6, lane = tid & 63;
  const int row_l = lane & 15, kg = lane >> 4;
  // XCD-chunked swizzle: 1024 wgs -> 128 contiguous per XCD = 16 batches/XCD.
  const int wg = blockIdx.y * 8 + blockIdx.x;
  const int idx = (wg & 7) * 128 + (wg >> 3);
  const int batch = idx >> 3, qt2 = idx & 7;
  const int q0 = qt2 * 128;
  const unsigned short* Qb = Q + (size_t)batch * 65536;
  const unsigned short* Kb = Km + (size_t)batch * 65536;
  const unsigned short* Vb = Vt + (size_t)batch * 65536;
  const unsigned int* mT = mbitsT + (size_t)(batch & 7) * 32768;
  float* attb = attn + (size_t)batch * 1048576;
  const int q_loc = wave * 16 + row_l;   // lane's row within each 64-tile
  const int qA = q0 + q_loc;             // global q row, tile A
  const int qB = q0 + 64 + q_loc;        // global q row, tile B

#define STAGE_K_TO(kt, dst)                                                           \
  {                                                                                   \
    _Pragma("unroll") for (int it = 0; it < 2; ++it) {                                \
      int c = wave * 64 + it * 256 + lane;                                            \
      int r_ = c >> 3, ch_ = c & 7, sch_ = ch_ ^ (r_ & 7);                            \
      gload16(Kb + (size_t)((kt) * 64 + r_) * 64 + sch_ * 8,                          \
              (dst) + (wave * 64 + it * 256) * 8);                                    \
    }                                                                                 \
  }
#define STAGE_V_TO(kt, dst)                                                           \
  {                                                                                   \
    _Pragma("unroll") for (int it = 0; it < 2; ++it) {                                \
      int c = wave * 64 + it * 256 + lane;                                            \
      int r_ = c >> 3, ch_ = c & 7, sch_ = ch_ ^ (r_ & 7);                            \
      gload16(Vb + (size_t)r_ * 1024 + (kt) * 64 + sch_ * 8,                          \
              (dst) + (wave * 64 + it * 256) * 8);                                    \
    }                                                                                 \
  }
#define WAIT_BAR0                                             \
  asm volatile("s_waitcnt vmcnt(0)" ::: "memory");            \
  __builtin_amdgcn_s_barrier();

  // QK^T for one tile from lK with a given q fragment -> s[4]
#define QKT(sdst, kbuf, qfrag)                                                        \
  {                                                                                   \
    __builtin_amdgcn_s_setprio(1);                                                    \
    _Pragma("unroll") for (int cf = 0; cf < 4; ++cf) {                                \
      int rk = cf * 16 + row_l;                                                       \
      f32x4 a_ = {0.f, 0.f, 0.f, 0.f};                                                \
      _Pragma("unroll") for (int kk = 0; kk < 2; ++kk) {                              \
        short8 kf = *(const short8*)((kbuf) + rk * 64 + (((kk * 4 + kg) ^ (rk & 7)) << 3)); \
        a_ = __builtin_amdgcn_mfma_f32_16x16x32_bf16(kf, (qfrag)[kk], a_, 0, 0, 0);   \
      }                                                                               \
      (sdst)[cf] = a_;                                                                \
    }                                                                                 \
    __builtin_amdgcn_s_setprio(0);                                                    \
  }

  // ---- prologue: stage QA+QB (16KB) + K[0] ----
#pragma unroll
  for (int it = 0; it < 4; ++it) {
    int c = wave * 64 + it * 256 + lane;          // 0..1023 -> rows 0..127
    int r = c >> 3, ch = c & 7;
    int sch = ch ^ (r & 7);
    gload16(Qb + (size_t)(q0 + r) * 64 + sch * 8, lQ + (wave * 64 + it * 256) * 8);
  }
  STAGE_K_TO(0, lK)
  WAIT_BAR0
  short8 qfA[2], qfB[2];
#pragma unroll
  for (int kk = 0; kk < 2; ++kk) {
    qfA[kk] = *(const short8*)(lQ + q_loc * 64 + (((kk * 4 + kg) ^ (q_loc & 7)) << 3));
    int rB = 64 + q_loc;
    qfB[kk] = *(const short8*)(lQ + rB * 64 + (((kk * 4 + kg) ^ (rB & 7)) << 3));
  }

  // ---- PASS 1(A): sums for tile A ----
  float l_partA = 0.f;
  for (int kt = 0; kt < 16; ++kt) {
    unsigned int mw0 = mT[(kt * 2 + 0) * 1024 + qA];
    unsigned int mw1 = mT[(kt * 2 + 1) * 1024 + qA];
    f32x4 s[4];
    QKT(s, lK, qfA)
#pragma unroll
    for (int cf = 0; cf < 4; ++cf) {
      unsigned int w = (cf < 2) ? mw0 : mw1;
#pragma unroll
      for (int r = 0; r < 4; ++r) {
        int bit = (w >> ((cf & 1) * 16 + kg * 4 + r)) & 1;
        float e = __builtin_exp2f(s[cf][r] * EXP_C);
        l_partA += bit ? 0.f : e;
      }
    }
    __syncthreads();
    if (kt < 15) {
      STAGE_K_TO(kt + 1, lK)
      WAIT_BAR0
    }
  }
  float seA = l_partA;
  seA += __shfl_xor(seA, 16);
  seA += __shfl_xor(seA, 32);
  const float ilA = 1.f / seA;

  unsigned short* lPA = lQ;              // rows 0..63 (QA dead)
  unsigned short* lPB = lQ + 64 * 64;    // rows 0..63 (QB dead)
  f32x4 caccA[4] = {};
  f32x4 caccB[4] = {};
  float l_partB = 0.f;

  // ---- MID-LOOP: pass1(B) + pass2(A) share each K tile; V staged for PV(A) ----
  for (int kt = 0; kt < 16; ++kt) {
    __syncthreads();                     // prior readers of lK/lV done
    STAGE_K_TO(kt, lK)
    STAGE_V_TO(kt, lV)
    unsigned int mwA0 = mT[(kt * 2 + 0) * 1024 + qA];
    unsigned int mwA1 = mT[(kt * 2 + 1) * 1024 + qA];
    unsigned int mwB0 = mT[(kt * 2 + 0) * 1024 + qB];
    unsigned int mwB1 = mT[(kt * 2 + 1) * 1024 + qB];
    WAIT_BAR0
    // pass1(B): sums
    {
      f32x4 s[4];
      QKT(s, lK, qfB)
#pragma unroll
      for (int cf = 0; cf < 4; ++cf) {
        unsigned int w = (cf < 2) ? mwB0 : mwB1;
#pragma unroll
        for (int r = 0; r < 4; ++r) {
          int bit = (w >> ((cf & 1) * 16 + kg * 4 + r)) & 1;
          float e = __builtin_exp2f(s[cf][r] * EXP_C);
          l_partB += bit ? 0.f : e;
        }
      }
    }
    // pass2(A): P write + PV
    {
      f32x4 s[4];
      QKT(s, lK, qfA)
#pragma unroll
      for (int cf = 0; cf < 4; ++cf) {
        unsigned int w = (cf < 2) ? mwA0 : mwA1;
        f32x4 o;
        unsigned short pb[4];
#pragma unroll
        for (int r = 0; r < 4; ++r) {
          int bit = (w >> ((cf & 1) * 16 + kg * 4 + r)) & 1;
          float p = bit ? 0.f : __builtin_exp2f(s[cf][r] * EXP_C) * ilA;
          o[r] = p;
          pb[r] = f2bf(p);
        }
        int swc = (cf * 2 + (kg >> 1)) ^ (q_loc & 7);
        *(uint2*)((char*)lPA + q_loc * 128 + swc * 16 + (kg & 1) * 8) = *(const uint2*)pb;
        __builtin_nontemporal_store(
            o, (f32x4*)(attb + (size_t)qA * 1024 + kt * 64 + cf * 16 + kg * 4));
      }
      __builtin_amdgcn_s_setprio(1);
#pragma unroll
      for (int kk = 0; kk < 2; ++kk) {
        short8 pa = *(const short8*)(lPA + q_loc * 64 + (((kk * 4 + kg) ^ (q_loc & 7)) << 3));
#pragma unroll
        for (int df = 0; df < 4; ++df) {
          int rv = df * 16 + row_l;
          short8 vb = *(const short8*)(lV + rv * 64 + (((kk * 4 + kg) ^ (rv & 7)) << 3));
          caccA[df] = __builtin_amdgcn_mfma_f32_16x16x32_bf16(pa, vb, caccA[df], 0, 0, 0);
        }
      }
      __builtin_amdgcn_s_setprio(0);
    }
  }
  float seB = l_partB;
  seB += __shfl_xor(seB, 16);
  seB += __shfl_xor(seB, 32);
  const float ilB = 1.f / seB;

  // ---- PASS 2(B): P write + PV ----
  for (int kt = 0; kt < 16; ++kt) {
    __syncthreads();
    STAGE_K_TO(kt, lK)
    STAGE_V_TO(kt, lV)
    unsigned int mw0 = mT[(kt * 2 + 0) * 1024 + qB];
    unsigned int mw1 = mT[(kt * 2 + 1) * 1024 + qB];
    WAIT_BAR0
    f32x4 s[4];
    QKT(s, lK, qfB)
#pragma unroll
    for (int cf = 0; cf < 4; ++cf) {
      unsigned int w = (cf < 2) ? mw0 : mw1;
      f32x4 o;
      unsigned short pb[4];
#pragma unroll
      for (int r = 0; r < 4; ++r) {
        int bit = (w >> ((cf & 1) * 16 + kg * 4 + r)) & 1;
        float p = bit ? 0.f : __builtin_exp2f(s[cf][r] * EXP_C) * ilB;
        o[r] = p;
        pb[r] = f2bf(p);
      }
      int swc = (cf * 2 + (kg >> 1)) ^ (q_loc & 7);
      *(uint2*)((char*)lPB + q_loc * 128 + swc * 16 + (kg & 1) * 8) = *(const uint2*)pb;
      __builtin_nontemporal_store(
          o, (f32x4*)(attb + (size_t)qB * 1024 + kt * 64 + cf * 16 + kg * 4));
    }
    __builtin_amdgcn_s_setprio(1);
#pragma unroll
    for (int kk = 0; kk < 2; ++kk) {
      short8 pa = *(const short8*)(lPB + q_loc * 64 + (((kk * 4 + kg) ^ (q_loc & 7)) << 3));
#pragma unroll
      for (int df = 0; df < 4; ++df) {
        int rv = df * 16 + row_l;
        short8 vb = *(const short8*)(lV + rv * 64 + (((kk * 4 + kg) ^ (rv & 7)) << 3));
        caccB[df] = __builtin_amdgcn_mfma_f32_16x16x32_bf16(pa, vb, caccB[df], 0, 0, 0);
      }
    }
    __builtin_amdgcn_s_setprio(0);
  }
  // ---- ctx stores for both tiles ----
#pragma unroll
  for (int df = 0; df < 4; ++df)
#pragma unroll
    for (int r = 0; r < 4; ++r) {
      int rowA = q0 + wave * 16 + kg * 4 + r;
      int gcol = df * 16 + row_l;
      ctx[(size_t)batch * 65536 + (size_t)rowA * 64 + gcol] = f2bf(caccA[df][r]);
      ctx[(size_t)batch * 65536 + (size_t)(rowA + 64) * 64 + gcol] = f2bf(caccB[df][r]);
    }
#undef STAGE_K_TO
#undef STAGE_V_TO
#undef WAIT_BAR0
#undef QKT
}

// ---------- layernorm, in-place on [8192][1024] f32, one wave per row ----------
__global__ __launch_bounds__(256) void layernorm_kernel(float* __restrict__ io,
                                                        const float* __restrict__ gamma,
                                                        const float* __restrict__ beta) {
  int wave = threadIdx.x >> 6, lane = threadIdx.x & 63;
  size_t row = (size_t)blockIdx.x * 4 + wave;
  float* p = io + row * 1024;
  float4 v[4];
  float s = 0.f, ss = 0.f;
#pragma unroll
  for (int i = 0; i < 4; ++i) {
    v[i] = ((const float4*)p)[lane + i * 64];
    s += v[i].x + v[i].y + v[i].z + v[i].w;
    ss += v[i].x * v[i].x + v[i].y * v[i].y + v[i].z * v[i].z + v[i].w * v[i].w;
  }
#pragma unroll
  for (int m = 1; m < 64; m <<= 1) { s += __shfl_xor(s, m); ss += __shfl_xor(ss, m); }
  float mu = s * (1.f / 1024.f);
  float var = ss * (1.f / 1024.f) - mu * mu;
  float rinv = rsqrtf(var + 1e-5f);
#pragma unroll
  for (int i = 0; i < 4; ++i) {
    int idx = lane + i * 64;
    float4 g = ((const float4*)gamma)[idx];
    float4 b = ((const float4*)beta)[idx];
    float4 o;
    o.x = (v[i].x - mu) * rinv * g.x + b.x;
    o.y = (v[i].y - mu) * rinv * g.y + b.y;
    o.z = (v[i].z - mu) * rinv * g.z + b.z;
    o.w = (v[i].w - mu) * rinv * g.w + b.w;
    ((float4*)p)[idx] = o;
  }
}

// ---------- host launch ----------
extern "C" void kernel_launch(void* const* d_in, const int* in_sizes, int n_in,
                              void* d_out, int out_size, void* d_ws, size_t ws_size,
                              hipStream_t stream) {
  const float* key   = (const float*)d_in[0];
  const float* value = (const float*)d_in[1];
  const float* query = (const float*)d_in[2];
  const int* amask   = (const int*)d_in[3];
  const float* Wq = (const float*)d_in[4];
  const float* bq = (const float*)d_in[5];
  const float* Wk = (const float*)d_in[6];
  const float* bk = (const float*)d_in[7];
  const float* Wv = (const float*)d_in[8];
  const float* bv = (const float*)d_in[9];
  const float* Wo = (const float*)d_in[10];
  const float* bo = (const float*)d_in[11];
  const float* gamma = (const float*)d_in[12];
  const float* beta  = (const float*)d_in[13];

  char* ws = (char*)d_ws;
  const size_t MB = 1024 * 1024;
  float* out_f = (float*)d_out;                       // [8192][1024]
  float* attn_f = (float*)d_out + (size_t)8388608;    // [128][1024][1024]
  const int n4 = 8388608 / 4;
  dim3 gemm_grid(8, 64);
  dim3 gemm_grid3(8, 64, 3);
  dim3 attn_grid(8, 128);   // 1024 two-tile blocks

  const bool big_ws = ws_size >= 106 * MB;
  if (big_ws) {
    unsigned short* A0 = (unsigned short*)(ws + 0);        // query bf16
    unsigned short* A1 = (unsigned short*)(ws + 16 * MB);  // key bf16, later vt
    unsigned short* A2 = (unsigned short*)(ws + 32 * MB);  // value bf16, later ctx
    unsigned short* B1 = (unsigned short*)(ws + 48 * MB);  // q
    unsigned short* B2 = (unsigned short*)(ws + 64 * MB);  // k
    unsigned short* B3 = (unsigned short*)(ws + 80 * MB);  // v [l][d]
    unsigned short* Wts = (unsigned short*)(ws + 96 * MB); // 4 x 2MB bf16
    unsigned int* mbitsT = (unsigned int*)(ws + 104 * MB); // 1 MB

    prep_kernel<<<61440, 256, 0, stream>>>(Wq, Wk, Wv, Wo, Wts, amask, mbitsT,
                                           query, key, value, A0, A1, A2);
    gemm_qkv_kernel<<<gemm_grid3, 256, 0, stream>>>(A0, A1, A2, Wts, bq, bk, bv, B1, B2, B3);
    transpose_v<<<dim3(2, 32, 128), 256, 0, stream>>>(B3, A1);   // key bf16 dead
    attn_kernel<<<attn_grid, 256, 0, stream>>>(B1, B2, A1, mbitsT, attn_f, A2);
    gemm_out_kernel<<<gemm_grid, 256, 0, stream>>>(A2, Wts + 3 * MB, bo, query, out_f);
    layernorm_kernel<<<2048, 256, 0, stream>>>(out_f, gamma, beta);
  } else {
    unsigned short* B0 = (unsigned short*)(ws + 0);        // conv scratch, later vt
    unsigned short* B1 = (unsigned short*)(ws + 16 * MB);  // q
    unsigned short* B2 = (unsigned short*)(ws + 32 * MB);  // k
    unsigned short* B3 = (unsigned short*)(ws + 48 * MB);  // v, later ctx
    unsigned short* Wts = (unsigned short*)(ws + 64 * MB);
    unsigned int* mbitsT = (unsigned int*)(ws + 72 * MB);

    prep_kernel<<<36864, 256, 0, stream>>>(Wq, Wk, Wv, Wo, Wts, amask, mbitsT,
                                           query, key, value, B0, B0, B0);
    conv_bf16<<<8192, 256, 0, stream>>>(query, B0, n4);
    gemm_qkv_kernel<<<gemm_grid, 256, 0, stream>>>(B0, B0, B0, Wts, bq, bq, bq, B1, B1, B1);
    conv_bf16<<<8192, 256, 0, stream>>>(key, B0, n4);
    gemm_qkv_kernel<<<gemm_grid, 256, 0, stream>>>(B0, B0, B0, Wts + 1 * MB, bk, bk, bk, B2, B2, B2);
    conv_bf16<<<8192, 256, 0, stream>>>(value, B0, n4);
    gemm_qkv_kernel<<<gemm_grid, 256, 0, stream>>>(B0, B0, B0, Wts + 2 * MB, bv, bv, bv, B3, B3, B3);
    transpose_v<<<dim3(2, 32, 128), 256, 0, stream>>>(B3, B0);
    attn_kernel<<<attn_grid, 256, 0, stream>>>(B1, B2, B0, mbitsT, attn_f, B3);
    gemm_out_kernel<<<gemm_grid, 256, 0, stream>>>(B3, Wts + 3 * MB, bo, query, out_f);
    layernorm_kernel<<<2048, 256, 0, stream>>>(out_f, gamma, beta);
  }
}

// Round 17
// 319.915 us; speedup vs baseline: 1.3375x; 1.3375x over previous
//
#include <hip/hip_runtime.h>

// ---------- types / helpers ----------
typedef __attribute__((ext_vector_type(8))) short short8;
typedef __attribute__((ext_vector_type(4))) float f32x4;

#define AS1C(p) ((const __attribute__((address_space(1))) void*)(p))
#define AS3(p)  ((__attribute__((address_space(3))) void*)(p))

__device__ __forceinline__ unsigned short f2bf(float f) {
  unsigned int u = __float_as_uint(f);
  return (unsigned short)((u + 0x7fffu + ((u >> 16) & 1u)) >> 16);
}

__device__ __forceinline__ void gload16(const void* g, void* l) {
  // 16B global -> LDS direct; LDS dest = wave-uniform base + lane*16
  __builtin_amdgcn_global_load_lds(AS1C(g), AS3(l), 16, 0, 0);
}

// exp(s/8) = exp2(s * 0.125*log2(e))
#define EXP_C 0.18033688011112042f

// ---------- merged prep: W transpose (0..4095) + mask pack (4096..36863) + f32->bf16 conv (36864..61439) ----------
__global__ __launch_bounds__(256) void prep_kernel(const float* __restrict__ W0,
                                                   const float* __restrict__ W1,
                                                   const float* __restrict__ W2,
                                                   const float* __restrict__ W3,
                                                   unsigned short* __restrict__ WtBase,
                                                   const int* __restrict__ m,
                                                   unsigned int* __restrict__ bitsT,
                                                   const float* __restrict__ s0,
                                                   const float* __restrict__ s1,
                                                   const float* __restrict__ s2,
                                                   unsigned short* __restrict__ d0,
                                                   unsigned short* __restrict__ d1,
                                                   unsigned short* __restrict__ d2) {
  int bid = blockIdx.x;
  if (bid < 4096) {
    __shared__ float t[32][33];
    int z = bid >> 10;              // 0..3: which W
    int rb = bid & 1023;            // 32x32 tile id
    int bx = (rb & 31) * 32, by = (rb >> 5) * 32;
    const float* W = (z == 0) ? W0 : (z == 1) ? W1 : (z == 2) ? W2 : W3;
    unsigned short* Wt = WtBase + (size_t)z * 1024 * 1024;
    int tx = threadIdx.x & 31, ty = threadIdx.x >> 5;  // 32 x 8
#pragma unroll
    for (int i = 0; i < 4; ++i) {
      int r = ty + i * 8;
      t[r][tx] = W[(size_t)(by + r) * 1024 + bx + tx];
    }
    __syncthreads();
#pragma unroll
    for (int i = 0; i < 4; ++i) {
      int r = ty + i * 8;
      Wt[(size_t)(bx + r) * 1024 + by + tx] = f2bf(t[tx][r]);
    }
  } else if (bid < 36864) {
    int i = (bid - 4096) * 256 + threadIdx.x;   // over 8M mask elements: b*1M + q*1024 + k
    unsigned long long bl = __ballot(m[i] != 0);
    if ((threadIdx.x & 63) == 0) {
      int b_ = i >> 20, q = (i >> 10) & 1023, k = i & 1023;
      int w = k >> 5;
      bitsT[b_ * 32768 + w * 1024 + q]       = (unsigned int)bl;
      bitsT[b_ * 32768 + (w + 1) * 1024 + q] = (unsigned int)(bl >> 32);
    }
  } else {
    int cb = bid - 36864;                       // 0..24575
    int z = cb >> 13;                           // 0..2 (8192 blocks each)
    const float* in = (z == 0) ? s0 : (z == 1) ? s1 : s2;
    unsigned short* out = (z == 0) ? d0 : (z == 1) ? d1 : d2;
    int i = (cb & 8191) * 256 + threadIdx.x;    // over 2M float4
    float4 v = ((const float4*)in)[i];
    ushort4 o;
    o.x = f2bf(v.x); o.y = f2bf(v.y); o.z = f2bf(v.z); o.w = f2bf(v.w);
    ((ushort4*)out)[i] = o;
  }
}

// ---------- standalone f32 -> bf16 convert (small-ws fallback path) ----------
__global__ __launch_bounds__(256) void conv_bf16(const float* __restrict__ in,
                                                 unsigned short* __restrict__ out, int n4) {
  int i = blockIdx.x * 256 + threadIdx.x;
  if (i >= n4) return;
  float4 v = ((const float4*)in)[i];
  ushort4 o;
  o.x = f2bf(v.x); o.y = f2bf(v.y); o.z = f2bf(v.z); o.w = f2bf(v.w);
  ((ushort4*)out)[i] = o;
}

// ---------- v [128][1024][64] bf16 -> vt [128][64][1024] bf16 (raw flat view) ----------
__global__ __launch_bounds__(256) void transpose_v(const unsigned short* __restrict__ v,
                                                   unsigned short* __restrict__ vt) {
  __shared__ unsigned short t[32][33];
  int b = blockIdx.z;
  int bx = blockIdx.x * 32;  // d tile (0,32)
  int by = blockIdx.y * 32;  // k tile
  int tx = threadIdx.x & 31, ty = threadIdx.x >> 5;
#pragma unroll
  for (int i = 0; i < 4; ++i) {
    int r = ty + i * 8;
    t[r][tx] = v[(size_t)b * 65536 + (size_t)(by + r) * 64 + bx + tx];
  }
  __syncthreads();
#pragma unroll
  for (int i = 0; i < 4; ++i) {
    int r = ty + i * 8;
    vt[(size_t)b * 65536 + (size_t)(bx + r) * 1024 + by + tx] = t[tx][r];
  }
}

// ---------- bf16 GEMM tile body, BK=64 (R14-proven) ----------
// MODE 0: Cb = bf16(acc + bias).  MODE 1: Cf = acc + bias + res (f32).
template <int MODE>
__device__ __forceinline__ void gemm_body(
    const unsigned short* __restrict__ A, const unsigned short* __restrict__ Bt,
    const float* __restrict__ bias, const float* __restrict__ res,
    unsigned short* __restrict__ Cb, float* __restrict__ Cf,
    unsigned short* lA, unsigned short* lB) {
  const int K = 1024, N = 1024;
  const int tid = threadIdx.x;
  const int wave = tid >> 6, lane = tid & 63;
  const int row_l = lane & 15, kg = lane >> 4;
  const int wg = blockIdx.y * 8 + blockIdx.x;
  const int idx = (wg & 7) * 64 + (wg >> 3);
  const int m0 = (idx >> 3) * 128, n0 = (idx & 7) * 128;
  const int wm = (wave >> 1) * 64, wn = (wave & 1) * 64;
  f32x4 acc[4][4] = {};

  for (int k0 = 0; k0 < K; k0 += 64) {
    __syncthreads();
#pragma unroll
    for (int it = 0; it < 4; ++it) {
      int c = wave * 64 + it * 256 + lane;
      int r = c >> 3, ch = c & 7;
      int sch = ch ^ (r & 7);
      gload16(A + (size_t)(m0 + r) * K + k0 + sch * 8, lA + (wave * 64 + it * 256) * 8);
      gload16(Bt + (size_t)(n0 + r) * K + k0 + sch * 8, lB + (wave * 64 + it * 256) * 8);
    }
    __syncthreads();
#pragma unroll
    for (int kk = 0; kk < 2; ++kk) {
      short8 af[4], bfr[4];
#pragma unroll
      for (int t = 0; t < 4; ++t) {
        int ra = wm + t * 16 + row_l;
        af[t] = *(const short8*)(lA + ra * 64 + (((kk * 4 + kg) ^ (ra & 7)) << 3));
        int rb = wn + t * 16 + row_l;
        bfr[t] = *(const short8*)(lB + rb * 64 + (((kk * 4 + kg) ^ (rb & 7)) << 3));
      }
      __builtin_amdgcn_s_setprio(1);
#pragma unroll
      for (int mt = 0; mt < 4; ++mt)
#pragma unroll
        for (int nt = 0; nt < 4; ++nt)
          acc[mt][nt] = __builtin_amdgcn_mfma_f32_16x16x32_bf16(af[mt], bfr[nt], acc[mt][nt], 0, 0, 0);
      __builtin_amdgcn_s_setprio(0);
    }
  }
#pragma unroll
  for (int mt = 0; mt < 4; ++mt)
#pragma unroll
    for (int nt = 0; nt < 4; ++nt)
#pragma unroll
      for (int r = 0; r < 4; ++r) {
        int grow = m0 + wm + mt * 16 + kg * 4 + r;
        int gcol = n0 + wn + nt * 16 + row_l;
        float v = acc[mt][nt][r] + bias[gcol];
        if (MODE == 0) {
          Cb[(size_t)grow * N + gcol] = f2bf(v);
        } else {
          v += res[(size_t)grow * N + gcol];
          Cf[(size_t)grow * N + gcol] = v;
        }
      }
}

// q,k,v projections in one launch (z picks tensors).
__global__ __launch_bounds__(256) void gemm_qkv_kernel(
    const unsigned short* __restrict__ A0, const unsigned short* __restrict__ A1,
    const unsigned short* __restrict__ A2, const unsigned short* __restrict__ WtBase,
    const float* __restrict__ b0, const float* __restrict__ b1, const float* __restrict__ b2,
    unsigned short* __restrict__ C0, unsigned short* __restrict__ C1,
    unsigned short* __restrict__ C2) {
  __shared__ unsigned short lA[128 * 64];
  __shared__ unsigned short lB[128 * 64];
  int z = blockIdx.z;
  const unsigned short* A = (z == 0) ? A0 : (z == 1) ? A1 : A2;
  const float* bias = (z == 0) ? b0 : (z == 1) ? b1 : b2;
  unsigned short* C = (z == 0) ? C0 : (z == 1) ? C1 : C2;
  gemm_body<0>(A, WtBase + (size_t)z * 1024 * 1024, bias, nullptr, C, nullptr, lA, lB);
}

__global__ __launch_bounds__(256) void gemm_out_kernel(
    const unsigned short* __restrict__ A, const unsigned short* __restrict__ Bt,
    const float* __restrict__ bias, const float* __restrict__ res, float* __restrict__ Cf) {
  __shared__ unsigned short lA[128 * 64];
  __shared__ unsigned short lB[128 * 64];
  gemm_body<1>(A, Bt, bias, res, nullptr, Cf, lA, lB);
}

// ---------- attention (R15-proven, verbatim): swapped-QK, NT wide P stores,
// pass-2 dbuf + counted vmcnt(4) ----------
__global__ __launch_bounds__(256) void attn_kernel(
    const unsigned short* __restrict__ Q,    // [128][1024][64]
    const unsigned short* __restrict__ Km,   // [128][1024][64]
    const unsigned short* __restrict__ Vt,   // [128][64][1024]
    const unsigned int* __restrict__ mbitsT, // [8][32 kwords][1024 q]
    float* __restrict__ attn,                // [128][1024][1024]
    unsigned short* __restrict__ ctx) {      // [128][1024][64]
  __shared__ unsigned short lQ[64 * 64];     // lQ (prologue) aliased with lP (pass 2)
  __shared__ unsigned short lK[2][64 * 64];
  __shared__ unsigned short lV[2][64 * 64];  // [d][k]
  const int tid = threadIdx.x, wave = tid >> 6, lane = tid & 63;
  const int row_l = lane & 15, kg = lane >> 4;
  const int wg = blockIdx.y * 16 + blockIdx.x;
  const int idx = (wg & 7) * 256 + (wg >> 3);
  const int batch = idx >> 4, qt = idx & 15;
  const int q0 = qt * 64;
  const unsigned short* Qb = Q + (size_t)batch * 65536;
  const unsigned short* Kb = Km + (size_t)batch * 65536;
  const unsigned short* Vb = Vt + (size_t)batch * 65536;
  const unsigned int* mT = mbitsT + (size_t)(batch & 7) * 32768;
  float* attb = attn + (size_t)batch * 1048576;
  const int q_loc = wave * 16 + row_l;
  const int q_lane = q0 + q_loc;

#define STAGE_K_TO(kt, dst)                                                           \
  {                                                                                   \
    _Pragma("unroll") for (int it = 0; it < 2; ++it) {                                \
      int c = wave * 64 + it * 256 + lane;                                            \
      int r_ = c >> 3, ch_ = c & 7, sch_ = ch_ ^ (r_ & 7);                            \
      gload16(Kb + (size_t)((kt) * 64 + r_) * 64 + sch_ * 8,                          \
              (dst) + (wave * 64 + it * 256) * 8);                                    \
    }                                                                                 \
  }
#define STAGE_V_TO(kt, dst)                                                           \
  {                                                                                   \
    _Pragma("unroll") for (int it = 0; it < 2; ++it) {                                \
      int c = wave * 64 + it * 256 + lane;                                            \
      int r_ = c >> 3, ch_ = c & 7, sch_ = ch_ ^ (r_ & 7);                            \
      gload16(Vb + (size_t)r_ * 1024 + (kt) * 64 + sch_ * 8,                          \
              (dst) + (wave * 64 + it * 256) * 8);                                    \
    }                                                                                 \
  }
#define WAIT_BAR0                                             \
  asm volatile("s_waitcnt vmcnt(0)" ::: "memory");            \
  __builtin_amdgcn_s_barrier();
#define WAIT_BAR4                                             \
  asm volatile("s_waitcnt vmcnt(4)" ::: "memory");            \
  __builtin_amdgcn_s_barrier();

  // ---- prologue: stage Q + K[0] (into lK[0]) ----
#pragma unroll
  for (int it = 0; it < 2; ++it) {
    int c = wave * 64 + it * 256 + lane;
    int r = c >> 3, ch = c & 7;
    int sch = ch ^ (r & 7);
    gload16(Qb + (size_t)(q0 + r) * 64 + sch * 8, lQ + (wave * 64 + it * 256) * 8);
  }
  STAGE_K_TO(0, lK[0])
  WAIT_BAR0
  short8 qf[2];
#pragma unroll
  for (int kk = 0; kk < 2; ++kk)
    qf[kk] = *(const short8*)(lQ + q_loc * 64 + (((kk * 4 + kg) ^ (q_loc & 7)) << 3));

  float l_part = 0.f;

  // ---- PASS 1: per-lane partial sum of exp; K dbuf; 1 barrier/iter ----
  auto pass1_step = [&](const unsigned short* kbuf, int kt) {
    unsigned int mw0 = mT[(kt * 2 + 0) * 1024 + q_lane];
    unsigned int mw1 = mT[(kt * 2 + 1) * 1024 + q_lane];
    f32x4 s[4];
    __builtin_amdgcn_s_setprio(1);
#pragma unroll
    for (int cf = 0; cf < 4; ++cf) {
      int rk = cf * 16 + row_l;
      f32x4 a = {0.f, 0.f, 0.f, 0.f};
#pragma unroll
      for (int kk = 0; kk < 2; ++kk) {
        short8 kf = *(const short8*)(kbuf + rk * 64 + (((kk * 4 + kg) ^ (rk & 7)) << 3));
        a = __builtin_amdgcn_mfma_f32_16x16x32_bf16(kf, qf[kk], a, 0, 0, 0);  // SWAPPED
      }
      s[cf] = a;
    }
    __builtin_amdgcn_s_setprio(0);
#pragma unroll
    for (int cf = 0; cf < 4; ++cf) {
      unsigned int w = (cf < 2) ? mw0 : mw1;
#pragma unroll
      for (int r = 0; r < 4; ++r) {
        int bit = (w >> ((cf & 1) * 16 + kg * 4 + r)) & 1;
        float e = __builtin_exp2f(s[cf][r] * EXP_C);
        l_part += bit ? 0.f : e;
      }
    }
  };
  for (int kt2 = 0; kt2 < 16; kt2 += 2) {
    STAGE_K_TO(kt2 + 1, lK[1])
    pass1_step(lK[0], kt2);
    WAIT_BAR0
    if (kt2 + 2 < 16) STAGE_K_TO(kt2 + 2, lK[0])
    pass1_step(lK[1], kt2 + 1);
    WAIT_BAR0
  }
  float se = l_part;
  se += __shfl_xor(se, 16);
  se += __shfl_xor(se, 32);
  const float il = 1.f / se;

  f32x4 cacc[4] = {};
  unsigned short* lP = lQ;

  // ---- PASS 2: dbuf staging; NT stores left in flight via counted vmcnt(4) ----
  STAGE_K_TO(0, lK[0])
  STAGE_V_TO(0, lV[0])
  WAIT_BAR0
  for (int kt = 0; kt < 16; ++kt) {
    int cur = kt & 1;
    const unsigned short* kb = lK[cur];
    const unsigned short* vbuf = lV[cur];
    // masks FIRST in issue order
    unsigned int mw0 = mT[(kt * 2 + 0) * 1024 + q_lane];
    unsigned int mw1 = mT[(kt * 2 + 1) * 1024 + q_lane];
    if (kt < 15) {
      STAGE_K_TO(kt + 1, lK[cur ^ 1])
      STAGE_V_TO(kt + 1, lV[cur ^ 1])
    }
    f32x4 s[4];
    __builtin_amdgcn_s_setprio(1);
#pragma unroll
    for (int cf = 0; cf < 4; ++cf) {
      int rk = cf * 16 + row_l;
      f32x4 a = {0.f, 0.f, 0.f, 0.f};
#pragma unroll
      for (int kk = 0; kk < 2; ++kk) {
        short8 kf = *(const short8*)(kb + rk * 64 + (((kk * 4 + kg) ^ (rk & 7)) << 3));
        a = __builtin_amdgcn_mfma_f32_16x16x32_bf16(kf, qf[kk], a, 0, 0, 0);  // SWAPPED
      }
      s[cf] = a;
    }
    __builtin_amdgcn_s_setprio(0);
#pragma unroll
    for (int cf = 0; cf < 4; ++cf) {
      unsigned int w = (cf < 2) ? mw0 : mw1;
      f32x4 o;
      unsigned short pb[4];
#pragma unroll
      for (int r = 0; r < 4; ++r) {
        int bit = (w >> ((cf & 1) * 16 + kg * 4 + r)) & 1;
        float p = bit ? 0.f : __builtin_exp2f(s[cf][r] * EXP_C) * il;
        o[r] = p;
        pb[r] = f2bf(p);
      }
      int swc = (cf * 2 + (kg >> 1)) ^ (q_loc & 7);
      *(uint2*)((char*)lP + q_loc * 128 + swc * 16 + (kg & 1) * 8) = *(const uint2*)pb;
      __builtin_nontemporal_store(
          o, (f32x4*)(attb + (size_t)q_lane * 1024 + kt * 64 + cf * 16 + kg * 4));
    }
    // no mid-barrier: lP rows are wave-private
    __builtin_amdgcn_s_setprio(1);
#pragma unroll
    for (int kk = 0; kk < 2; ++kk) {
      short8 pa = *(const short8*)(lP + q_loc * 64 + (((kk * 4 + kg) ^ (q_loc & 7)) << 3));
#pragma unroll
      for (int df = 0; df < 4; ++df) {
        int rv = df * 16 + row_l;
        short8 vb = *(const short8*)(vbuf + rv * 64 + (((kk * 4 + kg) ^ (rv & 7)) << 3));
        cacc[df] = __builtin_amdgcn_mfma_f32_16x16x32_bf16(pa, vb, cacc[df], 0, 0, 0);
      }
    }
    __builtin_amdgcn_s_setprio(0);
    // drain the 4 staging loads (older); leave the 4 NT stores in flight
    if (kt < 15) { WAIT_BAR4 } else { WAIT_BAR0 }
  }
#pragma unroll
  for (int df = 0; df < 4; ++df)
#pragma unroll
    for (int r = 0; r < 4; ++r) {
      int grow = q0 + wave * 16 + kg * 4 + r;
      int gcol = df * 16 + row_l;
      ctx[(size_t)batch * 65536 + (size_t)grow * 64 + gcol] = f2bf(cacc[df][r]);
    }
#undef STAGE_K_TO
#undef STAGE_V_TO
#undef WAIT_BAR0
#undef WAIT_BAR4
}

// ---------- layernorm, in-place on [8192][1024] f32, one wave per row ----------
__global__ __launch_bounds__(256) void layernorm_kernel(float* __restrict__ io,
                                                        const float* __restrict__ gamma,
                                                        const float* __restrict__ beta) {
  int wave = threadIdx.x >> 6, lane = threadIdx.x & 63;
  size_t row = (size_t)blockIdx.x * 4 + wave;
  float* p = io + row * 1024;
  float4 v[4];
  float s = 0.f, ss = 0.f;
#pragma unroll
  for (int i = 0; i < 4; ++i) {
    v[i] = ((const float4*)p)[lane + i * 64];
    s += v[i].x + v[i].y + v[i].z + v[i].w;
    ss += v[i].x * v[i].x + v[i].y * v[i].y + v[i].z * v[i].z + v[i].w * v[i].w;
  }
#pragma unroll
  for (int m = 1; m < 64; m <<= 1) { s += __shfl_xor(s, m); ss += __shfl_xor(ss, m); }
  float mu = s * (1.f / 1024.f);
  float var = ss * (1.f / 1024.f) - mu * mu;
  float rinv = rsqrtf(var + 1e-5f);
#pragma unroll
  for (int i = 0; i < 4; ++i) {
    int idx = lane + i * 64;
    float4 g = ((const float4*)gamma)[idx];
    float4 b = ((const float4*)beta)[idx];
    float4 o;
    o.x = (v[i].x - mu) * rinv * g.x + b.x;
    o.y = (v[i].y - mu) * rinv * g.y + b.y;
    o.z = (v[i].z - mu) * rinv * g.z + b.z;
    o.w = (v[i].w - mu) * rinv * g.w + b.w;
    ((float4*)p)[idx] = o;
  }
}

// ---------- host launch ----------
extern "C" void kernel_launch(void* const* d_in, const int* in_sizes, int n_in,
                              void* d_out, int out_size, void* d_ws, size_t ws_size,
                              hipStream_t stream) {
  const float* key   = (const float*)d_in[0];
  const float* value = (const float*)d_in[1];
  const float* query = (const float*)d_in[2];
  const int* amask   = (const int*)d_in[3];
  const float* Wq = (const float*)d_in[4];
  const float* bq = (const float*)d_in[5];
  const float* Wk = (const float*)d_in[6];
  const float* bk = (const float*)d_in[7];
  const float* Wv = (const float*)d_in[8];
  const float* bv = (const float*)d_in[9];
  const float* Wo = (const float*)d_in[10];
  const float* bo = (const float*)d_in[11];
  const float* gamma = (const float*)d_in[12];
  const float* beta  = (const float*)d_in[13];

  char* ws = (char*)d_ws;
  const size_t MB = 1024 * 1024;
  float* out_f = (float*)d_out;                       // [8192][1024]
  float* attn_f = (float*)d_out + (size_t)8388608;    // [128][1024][1024]
  const int n4 = 8388608 / 4;
  dim3 gemm_grid(8, 64);
  dim3 gemm_grid3(8, 64, 3);
  dim3 attn_grid(16, 128);

  const bool big_ws = ws_size >= 106 * MB;
  if (big_ws) {
    unsigned short* A0 = (unsigned short*)(ws + 0);        // query bf16
    unsigned short* A1 = (unsigned short*)(ws + 16 * MB);  // key bf16, later vt
    unsigned short* A2 = (unsigned short*)(ws + 32 * MB);  // value bf16, later ctx
    unsigned short* B1 = (unsigned short*)(ws + 48 * MB);  // q
    unsigned short* B2 = (unsigned short*)(ws + 64 * MB);  // k
    unsigned short* B3 = (unsigned short*)(ws + 80 * MB);  // v [l][d]
    unsigned short* Wts = (unsigned short*)(ws + 96 * MB); // 4 x 2MB bf16
    unsigned int* mbitsT = (unsigned int*)(ws + 104 * MB); // 1 MB

    prep_kernel<<<61440, 256, 0, stream>>>(Wq, Wk, Wv, Wo, Wts, amask, mbitsT,
                                           query, key, value, A0, A1, A2);
    gemm_qkv_kernel<<<gemm_grid3, 256, 0, stream>>>(A0, A1, A2, Wts, bq, bk, bv, B1, B2, B3);
    transpose_v<<<dim3(2, 32, 128), 256, 0, stream>>>(B3, A1);   // key bf16 dead
    attn_kernel<<<attn_grid, 256, 0, stream>>>(B1, B2, A1, mbitsT, attn_f, A2);
    gemm_out_kernel<<<gemm_grid, 256, 0, stream>>>(A2, Wts + 3 * MB, bo, query, out_f);
    layernorm_kernel<<<2048, 256, 0, stream>>>(out_f, gamma, beta);
  } else {
    unsigned short* B0 = (unsigned short*)(ws + 0);        // conv scratch, later vt
    unsigned short* B1 = (unsigned short*)(ws + 16 * MB);  // q
    unsigned short* B2 = (unsigned short*)(ws + 32 * MB);  // k
    unsigned short* B3 = (unsigned short*)(ws + 48 * MB);  // v, later ctx
    unsigned short* Wts = (unsigned short*)(ws + 64 * MB);
    unsigned int* mbitsT = (unsigned int*)(ws + 72 * MB);

    prep_kernel<<<36864, 256, 0, stream>>>(Wq, Wk, Wv, Wo, Wts, amask, mbitsT,
                                           query, key, value, B0, B0, B0);
    conv_bf16<<<8192, 256, 0, stream>>>(query, B0, n4);
    gemm_qkv_kernel<<<gemm_grid, 256, 0, stream>>>(B0, B0, B0, Wts, bq, bq, bq, B1, B1, B1);
    conv_bf16<<<8192, 256, 0, stream>>>(key, B0, n4);
    gemm_qkv_kernel<<<gemm_grid, 256, 0, stream>>>(B0, B0, B0, Wts + 1 * MB, bk, bk, bk, B2, B2, B2);
    conv_bf16<<<8192, 256, 0, stream>>>(value, B0, n4);
    gemm_qkv_kernel<<<gemm_grid, 256, 0, stream>>>(B0, B0, B0, Wts + 2 * MB, bv, bv, bv, B3, B3, B3);
    transpose_v<<<dim3(2, 32, 128), 256, 0, stream>>>(B3, B0);
    attn_kernel<<<attn_grid, 256, 0, stream>>>(B1, B2, B0, mbitsT, attn_f, B3);
    gemm_out_kernel<<<gemm_grid, 256, 0, stream>>>(B3, Wts + 3 * MB, bo, query, out_f);
    layernorm_kernel<<<2048, 256, 0, stream>>>(out_f, gamma, beta);
  }
}